// Round 3
// baseline (155.836 us; speedup 1.0000x reference)
//
#include <hip/hip_runtime.h>

typedef __attribute__((ext_vector_type(8))) short bf16x8;
typedef __attribute__((ext_vector_type(4))) float f32x4;

__device__ __forceinline__ unsigned short f2bf(float f) {
    unsigned int u = __float_as_uint(f);
    u += 0x7fffu + ((u >> 16) & 1u);
    return (unsigned short)(u >> 16);
}
__device__ __forceinline__ unsigned int pack2bf(float lo, float hi) {
    return (unsigned int)f2bf(lo) | ((unsigned int)f2bf(hi) << 16);
}
__device__ __forceinline__ void async_ld16(void* lds, const void* g) {
    __builtin_amdgcn_global_load_lds(
        (const __attribute__((address_space(1))) unsigned int*)g,
        (__attribute__((address_space(3))) unsigned int*)lds, 16, 0, 0);
}

// ---------------------------------------------------------------------------
// Kernel 0: convert x[8192x1024] f32 -> bf16 and Wq/Wk/Wv -> Wcat bf16.
// grid 4288 x 256, exactly one 8-elem vector per thread (no loop).
// ---------------------------------------------------------------------------
__global__ __launch_bounds__(256) void convert_bf16(
    const float* __restrict__ x,
    const float* __restrict__ Wq, const float* __restrict__ Wk,
    const float* __restrict__ Wv,
    unsigned short* __restrict__ xbf, unsigned short* __restrict__ Wcat)
{
    const size_t XN8 = (size_t)8192 * 1024 / 8;   // 1048576
    size_t i = (size_t)blockIdx.x * 256 + threadIdx.x;
    const float* src;
    unsigned short* dst;
    if (i < XN8) {
        src = x + i * 8;
        dst = xbf + i * 8;
    } else {
        size_t o = (i - XN8) * 8;
        int sel = (int)(o >> 17);  // 131072 elems per W
        const float* W = (sel == 0) ? Wq : ((sel == 1) ? Wk : Wv);
        src = W + (o & 131071);
        dst = Wcat + o;
    }
    float4 f0 = ((const float4*)src)[0];
    float4 f1 = ((const float4*)src)[1];
    uint4 u;
    u.x = pack2bf(f0.x, f0.y); u.y = pack2bf(f0.z, f0.w);
    u.z = pack2bf(f1.x, f1.y); u.w = pack2bf(f1.z, f1.w);
    *(uint4*)dst = u;
}

// ---------------------------------------------------------------------------
// Kernel 1: QKV GEMM (bf16).  Tile 32(M) x 128(N), BK=64, double-buffered
// global_load_lds staging with ONE barrier per K-iteration (prefetch issued
// before compute so the barrier's vmcnt drain is overlapped).
// grid = 768 blocks (256 m-tiles x 3 weights) -> 3 blocks/CU resident.
// ---------------------------------------------------------------------------
__global__ __launch_bounds__(256) void qkv_gemm(
    const unsigned short* __restrict__ xbf,
    const unsigned short* __restrict__ Wcat,
    const float* __restrict__ bq, const float* __restrict__ bk,
    const float* __restrict__ bv,
    unsigned short* __restrict__ Qg,
    unsigned short* __restrict__ Kg,
    unsigned short* __restrict__ Vtg)
{
    __shared__ unsigned short As[2][32 * 64];    // 4 KB x2
    __shared__ unsigned short Bs[2][128 * 64];   // 16 KB x2

    const int tid  = threadIdx.x;
    const int lane = tid & 63;
    const int w    = tid >> 6;
    const int quad = lane >> 4;
    const int ln   = lane & 15;
    const int lr   = lane >> 3;
    const int lc   = (lane & 7) * 8;

    const int bid   = blockIdx.x;
    const int mbase = (bid / 3) * 32;
    const int nb    = bid % 3;                  // 0=Q 1=K 2=V
    const unsigned short* Wsel = Wcat + (size_t)nb * 128 * 1024;
    const unsigned short* xrowA = xbf + (size_t)(mbase + w * 8 + lr) * 1024 + lc;

    f32x4 acc[2][2];
#pragma unroll
    for (int mt = 0; mt < 2; mt++)
#pragma unroll
        for (int nt = 0; nt < 2; nt++) acc[mt][nt] = (f32x4){0.f, 0.f, 0.f, 0.f};

    auto stage = [&](int kb, int p) {
        const int kcol = kb * 64;
        // A: 32x64 = 4 chunks of 8 rows; wave w stages chunk w
        async_ld16(&As[p][w * 512 + lane * 8], xrowA + kcol);
        // B: 128x64 = 16 chunks; wave w stages chunks w*4..w*4+3
#pragma unroll
        for (int j = 0; j < 4; j++) {
            int chunk = w * 4 + j;
            async_ld16(&Bs[p][chunk * 512 + lane * 8],
                       Wsel + (size_t)(chunk * 8 + lr) * 1024 + kcol + lc);
        }
    };

    stage(0, 0);
    __syncthreads();

    for (int kb = 0; kb < 16; kb++) {
        const int p = kb & 1;
        if (kb < 15) stage(kb + 1, p ^ 1);   // async prefetch, overlapped below
#pragma unroll
        for (int ks = 0; ks < 2; ks++) {
            bf16x8 a[2], b[2];
#pragma unroll
            for (int mt = 0; mt < 2; mt++)
                a[mt] = *(const bf16x8*)&As[p][(mt * 16 + ln) * 64 + ks * 32 + quad * 8];
#pragma unroll
            for (int nt = 0; nt < 2; nt++)
                b[nt] = *(const bf16x8*)&Bs[p][(w * 32 + nt * 16 + ln) * 64 + ks * 32 + quad * 8];
#pragma unroll
            for (int mt = 0; mt < 2; mt++)
#pragma unroll
                for (int nt = 0; nt < 2; nt++)
                    acc[mt][nt] = __builtin_amdgcn_mfma_f32_16x16x32_bf16(
                        a[mt], b[nt], acc[mt][nt], 0, 0, 0);
        }
        __syncthreads();  // drain overlapped by the compute above
    }

    const float scale = (nb == 0) ? 0.08838834764831845f : 1.0f;  // 1/sqrt(128)
    const float* bsel = (nb == 0) ? bq : ((nb == 1) ? bk : bv);
    float bias_v[2];
#pragma unroll
    for (int nt = 0; nt < 2; nt++) bias_v[nt] = bsel[w * 32 + nt * 16 + ln];

    if (nb < 2) {
        unsigned short* dst = (nb == 0) ? Qg : Kg;
#pragma unroll
        for (int mt = 0; mt < 2; mt++)
#pragma unroll
            for (int nt = 0; nt < 2; nt++)
#pragma unroll
                for (int r = 0; r < 4; r++) {
                    int m = mbase + mt * 16 + quad * 4 + r;
                    int d = w * 32 + nt * 16 + ln;
                    dst[(size_t)m * 128 + d] =
                        f2bf((acc[mt][nt][r] + bias_v[nt]) * scale);
                }
    } else {
#pragma unroll
        for (int mt = 0; mt < 2; mt++)
#pragma unroll
            for (int nt = 0; nt < 2; nt++) {
                int dd = w * 32 + nt * 16 + ln;
                int m0 = mbase + mt * 16 + quad * 4;
                int bb = m0 >> 11, s0 = m0 & 2047;
                ushort4 u = { f2bf(acc[mt][nt][0] + bias_v[nt]),
                              f2bf(acc[mt][nt][1] + bias_v[nt]),
                              f2bf(acc[mt][nt][2] + bias_v[nt]),
                              f2bf(acc[mt][nt][3] + bias_v[nt]) };
                *(ushort4*)&Vtg[((size_t)bb * 128 + dd) * 2048 + s0] = u;
            }
    }
}

// ---------------------------------------------------------------------------
// Kernel 2: causal flash attention, KV-split, double-buffered K/V staging via
// global_load_lds.  Q lives in registers (A-frags loaded straight from global).
// grid = (4 b, 32 qtile, 8 chunk), chunk c covers kt in [4c, min(4c+4,q+1)).
// ---------------------------------------------------------------------------
__global__ __launch_bounds__(256) void flash_attn(
    const unsigned short* __restrict__ Qg,
    const unsigned short* __restrict__ Kg,
    const unsigned short* __restrict__ Vtg,
    unsigned short* __restrict__ Opart,
    float2* __restrict__ ml)
{
    __shared__ unsigned short Ks[2][64 * 128];   // 16 KB x2
    __shared__ unsigned short Vts[2][128 * 64];  // 16 KB x2
    __shared__ unsigned short Pl[64][72];        // 9 KB

    const int b = blockIdx.x;
    const int q = blockIdx.y;
    const int c = blockIdx.z;
    if (c > (q >> 2)) return;

    const int m4 = q >> 2, r4 = q & 3;
    const int pidx = b * 144 + q + 2 * m4 * (m4 - 1) + r4 * m4 + c;
    const int k0 = c * 4;
    const int kend = (c * 4 + 4 < q + 1) ? (c * 4 + 4) : (q + 1);

    const int tid  = threadIdx.x;
    const int lane = tid & 63, w = tid >> 6, quad = lane >> 4, ln = lane & 15;

    // Q A-frags straight into registers (wave w owns q-rows w*16..w*16+15)
    bf16x8 qa[4];
    const unsigned short* qrow =
        Qg + ((size_t)b * 2048 + q * 64 + w * 16 + ln) * 128 + quad * 8;
#pragma unroll
    for (int ks = 0; ks < 4; ks++) qa[ks] = *(const bf16x8*)(qrow + ks * 32);

    auto stage = [&](int kt, int p) {
        const unsigned short* ksrc = Kg + ((size_t)b * 2048 + kt * 64) * 128;
#pragma unroll
        for (int j = 0; j < 4; j++) {            // K: 16 chunks of 4 rows
            int chunk = w * 4 + j;
            async_ld16(&Ks[p][chunk * 512 + lane * 8],
                       ksrc + (size_t)(chunk * 4 + (lane >> 4)) * 128 + (lane & 15) * 8);
        }
        const unsigned short* vsrc = Vtg + (size_t)b * 128 * 2048 + kt * 64;
#pragma unroll
        for (int j = 0; j < 4; j++) {            // V: 16 chunks of 8 d-rows
            int chunk = w * 4 + j;
            async_ld16(&Vts[p][chunk * 512 + lane * 8],
                       vsrc + (size_t)(chunk * 8 + (lane >> 3)) * 2048 + (lane & 7) * 8);
        }
    };

    float m_i[4], l_i[4];
    f32x4 Ofr[8];
#pragma unroll
    for (int r = 0; r < 4; r++) { m_i[r] = -__builtin_inff(); l_i[r] = 0.f; }
#pragma unroll
    for (int dt = 0; dt < 8; dt++) Ofr[dt] = (f32x4){0.f, 0.f, 0.f, 0.f};

    stage(k0, 0);
    __syncthreads();

    int p = 0;
    for (int kt = k0; kt < kend; kt++) {
        if (kt + 1 < kend) stage(kt + 1, p ^ 1);   // async prefetch

        // S = Q @ K^T  (overlaps the in-flight prefetch)
        f32x4 sfr[4];
#pragma unroll
        for (int ct = 0; ct < 4; ct++) {
            f32x4 s = (f32x4){0.f, 0.f, 0.f, 0.f};
#pragma unroll
            for (int ks = 0; ks < 4; ks++) {
                bf16x8 kf = *(const bf16x8*)&Ks[p][(ct * 16 + ln) * 128 + ks * 32 + quad * 8];
                s = __builtin_amdgcn_mfma_f32_16x16x32_bf16(qa[ks], kf, s, 0, 0, 0);
            }
            sfr[ct] = s;
        }

        if (kt == q) {  // diagonal tile: causal mask
#pragma unroll
            for (int ct = 0; ct < 4; ct++)
#pragma unroll
                for (int r = 0; r < 4; r++)
                    if (ct * 16 + ln > w * 16 + quad * 4 + r)
                        sfr[ct][r] = -__builtin_inff();
        }

        // online softmax
        float mrow[4];
#pragma unroll
        for (int r = 0; r < 4; r++) mrow[r] = -__builtin_inff();
#pragma unroll
        for (int ct = 0; ct < 4; ct++)
#pragma unroll
            for (int r = 0; r < 4; r++) mrow[r] = fmaxf(mrow[r], sfr[ct][r]);
#pragma unroll
        for (int off = 1; off < 16; off <<= 1)
#pragma unroll
            for (int r = 0; r < 4; r++)
                mrow[r] = fmaxf(mrow[r], __shfl_xor(mrow[r], off, 64));

        float alpha[4], rs[4];
#pragma unroll
        for (int r = 0; r < 4; r++) {
            float mn = fmaxf(m_i[r], mrow[r]);
            alpha[r] = __expf(m_i[r] - mn);
            m_i[r]   = mn;
            rs[r]    = 0.f;
        }
#pragma unroll
        for (int ct = 0; ct < 4; ct++)
#pragma unroll
            for (int r = 0; r < 4; r++) {
                float pv = __expf(sfr[ct][r] - m_i[r]);
                rs[r] += pv;
                Pl[w * 16 + quad * 4 + r][ct * 16 + ln] = f2bf(pv);
            }
#pragma unroll
        for (int off = 1; off < 16; off <<= 1)
#pragma unroll
            for (int r = 0; r < 4; r++) rs[r] += __shfl_xor(rs[r], off, 64);
#pragma unroll
        for (int r = 0; r < 4; r++) l_i[r] = l_i[r] * alpha[r] + rs[r];
#pragma unroll
        for (int dt = 0; dt < 8; dt++)
#pragma unroll
            for (int r = 0; r < 4; r++) Ofr[dt][r] *= alpha[r];

        __syncthreads();  // Pl visibility; prefetch drain overlapped by S+softmax

        // O += P @ V
#pragma unroll
        for (int kstep = 0; kstep < 2; kstep++) {
            bf16x8 pa = *(const bf16x8*)&Pl[w * 16 + ln][kstep * 32 + quad * 8];
#pragma unroll
            for (int dt = 0; dt < 8; dt++) {
                bf16x8 vf = *(const bf16x8*)&Vts[p][(dt * 16 + ln) * 64 + kstep * 32 + quad * 8];
                Ofr[dt] = __builtin_amdgcn_mfma_f32_16x16x32_bf16(pa, vf, Ofr[dt], 0, 0, 0);
            }
        }
        __syncthreads();  // WAR on Pl and Vts[p] before next iteration's writes
        p ^= 1;
    }

    // epilogue: unnormalized partials
#pragma unroll
    for (int dt = 0; dt < 8; dt++)
#pragma unroll
        for (int r = 0; r < 4; r++) {
            int row = w * 16 + quad * 4 + r;
            Opart[((size_t)pidx * 64 + row) * 128 + dt * 16 + ln] = f2bf(Ofr[dt][r]);
        }
    if (ln == 0) {
#pragma unroll
        for (int r = 0; r < 4; r++) {
            int row = w * 16 + quad * 4 + r;
            ml[(size_t)pidx * 64 + row] = make_float2(m_i[r], l_i[r]);
        }
    }
}

// ---------------------------------------------------------------------------
// Kernel 3: combine partials.  grid = 128 (b*32+q) x 256.
// Fixed 8-deep unrolled loops with clamped indices -> all loads issue in
// parallel; invalid chunks get weight exp(-inf)=0.
// ---------------------------------------------------------------------------
__global__ __launch_bounds__(256) void combine(
    const unsigned short* __restrict__ Opart,
    const float2* __restrict__ ml,
    float* __restrict__ out)
{
    const int b = blockIdx.x >> 5, q = blockIdx.x & 31;
    const int m4 = q >> 2, r4 = q & 3;
    const int pbase = b * 144 + q + 2 * m4 * (m4 - 1) + r4 * m4;
    const int nc = m4 + 1;

    const int row = threadIdx.x & 63;
    const int grp = (threadIdx.x >> 6) * 32;   // 32-col group per wave

    float2 t[8];
#pragma unroll
    for (int c2 = 0; c2 < 8; c2++) {
        int cc = (c2 < nc) ? c2 : (nc - 1);
        t[c2] = ml[(size_t)(pbase + cc) * 64 + row];
    }
    float mc[8], lc[8], wgt[8];
    float mmax = -__builtin_inff();
#pragma unroll
    for (int c2 = 0; c2 < 8; c2++) {
        mc[c2] = (c2 < nc) ? t[c2].x : -__builtin_inff();
        lc[c2] = (c2 < nc) ? t[c2].y : 0.f;
        mmax = fmaxf(mmax, mc[c2]);
    }
    float lsum = 0.f;
#pragma unroll
    for (int c2 = 0; c2 < 8; c2++) {
        wgt[c2] = __expf(mc[c2] - mmax);   // exp(-inf)=0 for invalid
        lsum += lc[c2] * wgt[c2];
    }
    const float inv = 1.0f / lsum;

#pragma unroll
    for (int v = 0; v < 4; v++) {
        int col = grp + v * 8;
        float acc[8];
#pragma unroll
        for (int k = 0; k < 8; k++) acc[k] = 0.f;
#pragma unroll
        for (int c2 = 0; c2 < 8; c2++) {
            int cc = (c2 < nc) ? c2 : (nc - 1);
            uint4 u = *(const uint4*)&Opart[((size_t)(pbase + cc) * 64 + row) * 128 + col];
            float wc = wgt[c2];
            acc[0] += wc * __uint_as_float(u.x << 16);
            acc[1] += wc * __uint_as_float(u.x & 0xffff0000u);
            acc[2] += wc * __uint_as_float(u.y << 16);
            acc[3] += wc * __uint_as_float(u.y & 0xffff0000u);
            acc[4] += wc * __uint_as_float(u.z << 16);
            acc[5] += wc * __uint_as_float(u.z & 0xffff0000u);
            acc[6] += wc * __uint_as_float(u.w << 16);
            acc[7] += wc * __uint_as_float(u.w & 0xffff0000u);
        }
        float* o = &out[((size_t)b * 2048 + q * 64 + row) * 128 + col];
        float4 o0 = { acc[0] * inv, acc[1] * inv, acc[2] * inv, acc[3] * inv };
        float4 o1 = { acc[4] * inv, acc[5] * inv, acc[6] * inv, acc[7] * inv };
        ((float4*)o)[0] = o0;
        ((float4*)o)[1] = o1;
    }
}

extern "C" void kernel_launch(void* const* d_in, const int* in_sizes, int n_in,
                              void* d_out, int out_size, void* d_ws, size_t ws_size,
                              hipStream_t stream) {
    const float* x  = (const float*)d_in[0];
    const float* Wq = (const float*)d_in[1];
    const float* bq = (const float*)d_in[2];
    const float* Wk = (const float*)d_in[3];
    const float* bk = (const float*)d_in[4];
    const float* Wv = (const float*)d_in[5];
    const float* bv = (const float*)d_in[6];
    float* out = (float*)d_out;

    // Workspace layout:
    //  region A [0, 17563648): phase 1-2: xbf (16 MB) + Wcat (768 KB)
    //                          phase 3-4: Opart (9 MB) + ml (288 KB)  (aliased)
    //  region B [17563648, ..): Qg (2 MB) + Kg (2 MB) + Vtg (2 MB)
    char* wsb = (char*)d_ws;
    unsigned short* xbf   = (unsigned short*)wsb;
    unsigned short* Wcat  = (unsigned short*)(wsb + 16777216);
    unsigned short* Opart = (unsigned short*)wsb;
    float2*         ml    = (float2*)(wsb + 9437184);
    unsigned short* Qg    = (unsigned short*)(wsb + 17563648);
    unsigned short* Kg    = Qg + (size_t)8192 * 128;
    unsigned short* Vtg   = Qg + (size_t)2 * 8192 * 128;

    convert_bf16<<<4288, 256, 0, stream>>>(x, Wq, Wk, Wv, xbf, Wcat);
    qkv_gemm<<<768, 256, 0, stream>>>(xbf, Wcat, bq, bk, bv, Qg, Kg, Vtg);
    flash_attn<<<dim3(4, 32, 8), 256, 0, stream>>>(Qg, Kg, Vtg, Opart, ml);
    combine<<<128, 256, 0, stream>>>(Opart, ml, out);
}

// Round 4
// 139.068 us; speedup vs baseline: 1.1206x; 1.1206x over previous
//
#include <hip/hip_runtime.h>

typedef __attribute__((ext_vector_type(8))) short bf16x8;
typedef __attribute__((ext_vector_type(4))) float f32x4;

__device__ __forceinline__ unsigned short f2bf(float f) {
    unsigned int u = __float_as_uint(f);
    u += 0x7fffu + ((u >> 16) & 1u);
    return (unsigned short)(u >> 16);
}
__device__ __forceinline__ unsigned int pack2bf(float lo, float hi) {
    return (unsigned int)f2bf(lo) | ((unsigned int)f2bf(hi) << 16);
}
__device__ __forceinline__ void async_ld16(void* lds, const void* g) {
    __builtin_amdgcn_global_load_lds(
        (const __attribute__((address_space(1))) unsigned int*)g,
        (__attribute__((address_space(3))) unsigned int*)lds, 16, 0, 0);
}

// ---------------------------------------------------------------------------
// Kernel 0: convert x[8192x1024] f32 -> bf16 and Wq/Wk/Wv -> Wcat bf16.
// ---------------------------------------------------------------------------
__global__ __launch_bounds__(256) void convert_bf16(
    const float* __restrict__ x,
    const float* __restrict__ Wq, const float* __restrict__ Wk,
    const float* __restrict__ Wv,
    unsigned short* __restrict__ xbf, unsigned short* __restrict__ Wcat)
{
    const size_t XN8 = (size_t)8192 * 1024 / 8;   // 1048576
    size_t i = (size_t)blockIdx.x * 256 + threadIdx.x;
    const float* src;
    unsigned short* dst;
    if (i < XN8) {
        src = x + i * 8;
        dst = xbf + i * 8;
    } else {
        size_t o = (i - XN8) * 8;
        int sel = (int)(o >> 17);  // 131072 elems per W
        const float* W = (sel == 0) ? Wq : ((sel == 1) ? Wk : Wv);
        src = W + (o & 131071);
        dst = Wcat + o;
    }
    float4 f0 = ((const float4*)src)[0];
    float4 f1 = ((const float4*)src)[1];
    uint4 u;
    u.x = pack2bf(f0.x, f0.y); u.y = pack2bf(f0.z, f0.w);
    u.z = pack2bf(f1.x, f1.y); u.w = pack2bf(f1.z, f1.w);
    *(uint4*)dst = u;
}

// ---------------------------------------------------------------------------
// Kernel 1: QKV GEMM (bf16).  Tile 32(M) x 128(N), BK=64, double-buffered
// global_load_lds staging, XOR-swizzled LDS layout:
//   chunk c (16B) of row r stored at slot (c ^ (r&7)) -> fragment ds_read_b128
//   hits 2 lanes/bank (free) instead of 16-way conflicts.
// grid = 768 blocks (256 m-tiles x 3 weights).
// ---------------------------------------------------------------------------
__global__ __launch_bounds__(256) void qkv_gemm(
    const unsigned short* __restrict__ xbf,
    const unsigned short* __restrict__ Wcat,
    const float* __restrict__ bq, const float* __restrict__ bk,
    const float* __restrict__ bv,
    unsigned short* __restrict__ Qg,
    unsigned short* __restrict__ Kg,
    unsigned short* __restrict__ Vtg)
{
    __shared__ unsigned short As[2][32 * 64];    // 4 KB x2
    __shared__ unsigned short Bs[2][128 * 64];   // 16 KB x2

    const int tid  = threadIdx.x;
    const int lane = tid & 63;
    const int w    = tid >> 6;
    const int quad = lane >> 4;
    const int ln   = lane & 15;
    const int lr   = lane >> 3;                 // 0..7 row-in-chunk
    const int csw  = ((lane & 7) ^ lr) * 8;     // swizzled source col (elems)

    const int bid   = blockIdx.x;
    const int mbase = (bid / 3) * 32;
    const int nb    = bid % 3;                  // 0=Q 1=K 2=V
    const unsigned short* Wsel = Wcat + (size_t)nb * 128 * 1024;

    f32x4 acc[2][2];
#pragma unroll
    for (int mt = 0; mt < 2; mt++)
#pragma unroll
        for (int nt = 0; nt < 2; nt++) acc[mt][nt] = (f32x4){0.f, 0.f, 0.f, 0.f};

    auto stage = [&](int kb, int p) {
        const int kcol = kb * 64 + csw;
        // A: 32x64 = 4 chunks of 8 rows; wave w stages chunk w
        async_ld16(&As[p][w * 512 + lane * 8],
                   xbf + (size_t)(mbase + w * 8 + lr) * 1024 + kcol);
        // B: 128x64 = 16 chunks; wave w stages chunks w*4..w*4+3
#pragma unroll
        for (int j = 0; j < 4; j++) {
            int chunk = w * 4 + j;
            async_ld16(&Bs[p][chunk * 512 + lane * 8],
                       Wsel + (size_t)(chunk * 8 + lr) * 1024 + kcol);
        }
    };

    stage(0, 0);
    __syncthreads();

    for (int kb = 0; kb < 16; kb++) {
        const int p = kb & 1;
        if (kb < 15) stage(kb + 1, p ^ 1);   // async prefetch, overlapped below
#pragma unroll
        for (int ks = 0; ks < 2; ks++) {
            bf16x8 a[2], b[2];
#pragma unroll
            for (int mt = 0; mt < 2; mt++) {
                int row = mt * 16 + ln;
                a[mt] = *(const bf16x8*)&As[p][row * 64 + ((ks * 4 + quad) ^ (ln & 7)) * 8];
            }
#pragma unroll
            for (int nt = 0; nt < 2; nt++) {
                int row = w * 32 + nt * 16 + ln;
                b[nt] = *(const bf16x8*)&Bs[p][row * 64 + ((ks * 4 + quad) ^ (ln & 7)) * 8];
            }
#pragma unroll
            for (int mt = 0; mt < 2; mt++)
#pragma unroll
                for (int nt = 0; nt < 2; nt++)
                    acc[mt][nt] = __builtin_amdgcn_mfma_f32_16x16x32_bf16(
                        a[mt], b[nt], acc[mt][nt], 0, 0, 0);
        }
        __syncthreads();
    }

    const float scale = (nb == 0) ? 0.08838834764831845f : 1.0f;  // 1/sqrt(128)
    const float* bsel = (nb == 0) ? bq : ((nb == 1) ? bk : bv);
    float bias_v[2];
#pragma unroll
    for (int nt = 0; nt < 2; nt++) bias_v[nt] = bsel[w * 32 + nt * 16 + ln];

    if (nb < 2) {
        unsigned short* dst = (nb == 0) ? Qg : Kg;
#pragma unroll
        for (int mt = 0; mt < 2; mt++)
#pragma unroll
            for (int nt = 0; nt < 2; nt++)
#pragma unroll
                for (int r = 0; r < 4; r++) {
                    int m = mbase + mt * 16 + quad * 4 + r;
                    int d = w * 32 + nt * 16 + ln;
                    dst[(size_t)m * 128 + d] =
                        f2bf((acc[mt][nt][r] + bias_v[nt]) * scale);
                }
    } else {
#pragma unroll
        for (int mt = 0; mt < 2; mt++)
#pragma unroll
            for (int nt = 0; nt < 2; nt++) {
                int dd = w * 32 + nt * 16 + ln;
                int m0 = mbase + mt * 16 + quad * 4;
                int bb = m0 >> 11, s0 = m0 & 2047;
                ushort4 u = { f2bf(acc[mt][nt][0] + bias_v[nt]),
                              f2bf(acc[mt][nt][1] + bias_v[nt]),
                              f2bf(acc[mt][nt][2] + bias_v[nt]),
                              f2bf(acc[mt][nt][3] + bias_v[nt]) };
                *(ushort4*)&Vtg[((size_t)bb * 128 + dd) * 2048 + s0] = u;
            }
    }
}

// ---------------------------------------------------------------------------
// Kernel 2: causal flash attention, KV-split, double-buffered swizzled K/V
// staging via global_load_lds; Q in registers.
// grid = (4 b, 32 qtile, 8 chunk), chunk c covers kt in [4c, min(4c+4,q+1)).
// K rows: 256B = 16 chunks, swizzle c^(row&15).  Vt rows: 128B = 8 chunks,
// swizzle c^(row&7).  Fragment reads land 2 lanes/bank (free).
// ---------------------------------------------------------------------------
__global__ __launch_bounds__(256) void flash_attn(
    const unsigned short* __restrict__ Qg,
    const unsigned short* __restrict__ Kg,
    const unsigned short* __restrict__ Vtg,
    unsigned short* __restrict__ Opart,
    float2* __restrict__ ml)
{
    __shared__ unsigned short Ks[2][64 * 128];   // 16 KB x2
    __shared__ unsigned short Vts[2][128 * 64];  // 16 KB x2
    __shared__ unsigned short Pl[64][72];        // 9 KB

    const int b = blockIdx.x;
    const int q = blockIdx.y;
    const int c = blockIdx.z;
    if (c > (q >> 2)) return;

    const int m4 = q >> 2, r4 = q & 3;
    const int pidx = b * 144 + q + 2 * m4 * (m4 - 1) + r4 * m4 + c;
    const int k0 = c * 4;
    const int kend = (c * 4 + 4 < q + 1) ? (c * 4 + 4) : (q + 1);

    const int tid  = threadIdx.x;
    const int lane = tid & 63, w = tid >> 6, quad = lane >> 4, ln = lane & 15;

    // Q A-frags straight into registers (wave w owns q-rows w*16..w*16+15)
    bf16x8 qa[4];
    const unsigned short* qrow =
        Qg + ((size_t)b * 2048 + q * 64 + w * 16 + ln) * 128 + quad * 8;
#pragma unroll
    for (int ks = 0; ks < 4; ks++) qa[ks] = *(const bf16x8*)(qrow + ks * 32);

    auto stage = [&](int kt, int p) {
        // K: 64 rows x 256B = 16 chunks of 1KB (4 rows each)
        const unsigned short* ksrc = Kg + ((size_t)b * 2048 + kt * 64) * 128;
        const int krl = lane >> 4;               // row in chunk
#pragma unroll
        for (int j = 0; j < 4; j++) {
            int chunk = w * 4 + j;
            int row = chunk * 4 + krl;
            int cd = (lane & 15) ^ (row & 15);
            async_ld16(&Ks[p][chunk * 512 + lane * 8],
                       ksrc + (size_t)row * 128 + cd * 8);
        }
        // Vt: 128 rows x 128B = 16 chunks of 1KB (8 rows each)
        const unsigned short* vsrc = Vtg + (size_t)b * 128 * 2048 + kt * 64;
        const int vrl = lane >> 3;
#pragma unroll
        for (int j = 0; j < 4; j++) {
            int chunk = w * 4 + j;
            int row = chunk * 8 + vrl;
            int cd = (lane & 7) ^ (row & 7);
            async_ld16(&Vts[p][chunk * 512 + lane * 8],
                       vsrc + (size_t)row * 2048 + cd * 8);
        }
    };

    float m_i[4], l_i[4];
    f32x4 Ofr[8];
#pragma unroll
    for (int r = 0; r < 4; r++) { m_i[r] = -__builtin_inff(); l_i[r] = 0.f; }
#pragma unroll
    for (int dt = 0; dt < 8; dt++) Ofr[dt] = (f32x4){0.f, 0.f, 0.f, 0.f};

    stage(k0, 0);
    __syncthreads();

    int p = 0;
    for (int kt = k0; kt < kend; kt++) {
        if (kt + 1 < kend) stage(kt + 1, p ^ 1);   // async prefetch

        // S = Q @ K^T  (overlaps the in-flight prefetch)
        f32x4 sfr[4];
#pragma unroll
        for (int ct = 0; ct < 4; ct++) {
            f32x4 s = (f32x4){0.f, 0.f, 0.f, 0.f};
#pragma unroll
            for (int ks = 0; ks < 4; ks++) {
                int row = ct * 16 + ln;
                bf16x8 kf = *(const bf16x8*)&Ks[p][row * 128 + ((ks * 4 + quad) ^ ln) * 8];
                s = __builtin_amdgcn_mfma_f32_16x16x32_bf16(qa[ks], kf, s, 0, 0, 0);
            }
            sfr[ct] = s;
        }

        if (kt == q) {  // diagonal tile: causal mask
#pragma unroll
            for (int ct = 0; ct < 4; ct++)
#pragma unroll
                for (int r = 0; r < 4; r++)
                    if (ct * 16 + ln > w * 16 + quad * 4 + r)
                        sfr[ct][r] = -__builtin_inff();
        }

        // online softmax
        float mrow[4];
#pragma unroll
        for (int r = 0; r < 4; r++) mrow[r] = -__builtin_inff();
#pragma unroll
        for (int ct = 0; ct < 4; ct++)
#pragma unroll
            for (int r = 0; r < 4; r++) mrow[r] = fmaxf(mrow[r], sfr[ct][r]);
#pragma unroll
        for (int off = 1; off < 16; off <<= 1)
#pragma unroll
            for (int r = 0; r < 4; r++)
                mrow[r] = fmaxf(mrow[r], __shfl_xor(mrow[r], off, 64));

        float alpha[4], rs[4];
#pragma unroll
        for (int r = 0; r < 4; r++) {
            float mn = fmaxf(m_i[r], mrow[r]);
            alpha[r] = __expf(m_i[r] - mn);
            m_i[r]   = mn;
            rs[r]    = 0.f;
        }
#pragma unroll
        for (int ct = 0; ct < 4; ct++)
#pragma unroll
            for (int r = 0; r < 4; r++) {
                float pv = __expf(sfr[ct][r] - m_i[r]);
                rs[r] += pv;
                Pl[w * 16 + quad * 4 + r][ct * 16 + ln] = f2bf(pv);
            }
#pragma unroll
        for (int off = 1; off < 16; off <<= 1)
#pragma unroll
            for (int r = 0; r < 4; r++) rs[r] += __shfl_xor(rs[r], off, 64);
#pragma unroll
        for (int r = 0; r < 4; r++) l_i[r] = l_i[r] * alpha[r] + rs[r];
#pragma unroll
        for (int dt = 0; dt < 8; dt++)
#pragma unroll
            for (int r = 0; r < 4; r++) Ofr[dt][r] *= alpha[r];

        __syncthreads();  // Pl visibility; prefetch drain overlapped by S+softmax

        // O += P @ V
#pragma unroll
        for (int kstep = 0; kstep < 2; kstep++) {
            bf16x8 pa = *(const bf16x8*)&Pl[w * 16 + ln][kstep * 32 + quad * 8];
#pragma unroll
            for (int dt = 0; dt < 8; dt++) {
                int row = dt * 16 + ln;
                bf16x8 vf = *(const bf16x8*)&Vts[p][row * 64 + ((kstep * 4 + quad) ^ (ln & 7)) * 8];
                Ofr[dt] = __builtin_amdgcn_mfma_f32_16x16x32_bf16(pa, vf, Ofr[dt], 0, 0, 0);
            }
        }
        __syncthreads();  // WAR on Pl and Vts[p] before next iteration's writes
        p ^= 1;
    }

    // epilogue: unnormalized partials
#pragma unroll
    for (int dt = 0; dt < 8; dt++)
#pragma unroll
        for (int r = 0; r < 4; r++) {
            int row = w * 16 + quad * 4 + r;
            Opart[((size_t)pidx * 64 + row) * 128 + dt * 16 + ln] = f2bf(Ofr[dt][r]);
        }
    if (ln == 0) {
#pragma unroll
        for (int r = 0; r < 4; r++) {
            int row = w * 16 + quad * 4 + r;
            ml[(size_t)pidx * 64 + row] = make_float2(m_i[r], l_i[r]);
        }
    }
}

// ---------------------------------------------------------------------------
// Kernel 3: combine partials.  grid = 128 (b*32+q) x 256.
// ---------------------------------------------------------------------------
__global__ __launch_bounds__(256) void combine(
    const unsigned short* __restrict__ Opart,
    const float2* __restrict__ ml,
    float* __restrict__ out)
{
    const int b = blockIdx.x >> 5, q = blockIdx.x & 31;
    const int m4 = q >> 2, r4 = q & 3;
    const int pbase = b * 144 + q + 2 * m4 * (m4 - 1) + r4 * m4;
    const int nc = m4 + 1;

    const int row = threadIdx.x & 63;
    const int grp = (threadIdx.x >> 6) * 32;   // 32-col group per wave

    float2 t[8];
#pragma unroll
    for (int c2 = 0; c2 < 8; c2++) {
        int cc = (c2 < nc) ? c2 : (nc - 1);
        t[c2] = ml[(size_t)(pbase + cc) * 64 + row];
    }
    float mc[8], lc[8], wgt[8];
    float mmax = -__builtin_inff();
#pragma unroll
    for (int c2 = 0; c2 < 8; c2++) {
        mc[c2] = (c2 < nc) ? t[c2].x : -__builtin_inff();
        lc[c2] = (c2 < nc) ? t[c2].y : 0.f;
        mmax = fmaxf(mmax, mc[c2]);
    }
    float lsum = 0.f;
#pragma unroll
    for (int c2 = 0; c2 < 8; c2++) {
        wgt[c2] = __expf(mc[c2] - mmax);   // exp(-inf)=0 for invalid
        lsum += lc[c2] * wgt[c2];
    }
    const float inv = 1.0f / lsum;

#pragma unroll
    for (int v = 0; v < 4; v++) {
        int col = grp + v * 8;
        float acc[8];
#pragma unroll
        for (int k = 0; k < 8; k++) acc[k] = 0.f;
#pragma unroll
        for (int c2 = 0; c2 < 8; c2++) {
            int cc = (c2 < nc) ? c2 : (nc - 1);
            uint4 u = *(const uint4*)&Opart[((size_t)(pbase + cc) * 64 + row) * 128 + col];
            float wc = wgt[c2];
            acc[0] += wc * __uint_as_float(u.x << 16);
            acc[1] += wc * __uint_as_float(u.x & 0xffff0000u);
            acc[2] += wc * __uint_as_float(u.y << 16);
            acc[3] += wc * __uint_as_float(u.y & 0xffff0000u);
            acc[4] += wc * __uint_as_float(u.z << 16);
            acc[5] += wc * __uint_as_float(u.z & 0xffff0000u);
            acc[6] += wc * __uint_as_float(u.w << 16);
            acc[7] += wc * __uint_as_float(u.w & 0xffff0000u);
        }
        float* o = &out[((size_t)b * 2048 + q * 64 + row) * 128 + col];
        float4 o0 = { acc[0] * inv, acc[1] * inv, acc[2] * inv, acc[3] * inv };
        float4 o1 = { acc[4] * inv, acc[5] * inv, acc[6] * inv, acc[7] * inv };
        ((float4*)o)[0] = o0;
        ((float4*)o)[1] = o1;
    }
}

extern "C" void kernel_launch(void* const* d_in, const int* in_sizes, int n_in,
                              void* d_out, int out_size, void* d_ws, size_t ws_size,
                              hipStream_t stream) {
    const float* x  = (const float*)d_in[0];
    const float* Wq = (const float*)d_in[1];
    const float* bq = (const float*)d_in[2];
    const float* Wk = (const float*)d_in[3];
    const float* bk = (const float*)d_in[4];
    const float* Wv = (const float*)d_in[5];
    const float* bv = (const float*)d_in[6];
    float* out = (float*)d_out;

    // Workspace layout:
    //  region A [0, 17563648): phase 1-2: xbf (16 MB) + Wcat (768 KB)
    //                          phase 3-4: Opart (9 MB) + ml (288 KB)  (aliased)
    //  region B [17563648, ..): Qg (2 MB) + Kg (2 MB) + Vtg (2 MB)
    char* wsb = (char*)d_ws;
    unsigned short* xbf   = (unsigned short*)wsb;
    unsigned short* Wcat  = (unsigned short*)(wsb + 16777216);
    unsigned short* Opart = (unsigned short*)wsb;
    float2*         ml    = (float2*)(wsb + 9437184);
    unsigned short* Qg    = (unsigned short*)(wsb + 17563648);
    unsigned short* Kg    = Qg + (size_t)8192 * 128;
    unsigned short* Vtg   = Qg + (size_t)2 * 8192 * 128;

    convert_bf16<<<4288, 256, 0, stream>>>(x, Wq, Wk, Wv, xbf, Wcat);
    qkv_gemm<<<768, 256, 0, stream>>>(xbf, Wcat, bq, bk, bv, Qg, Kg, Vtg);
    flash_attn<<<dim3(4, 32, 8), 256, 0, stream>>>(Qg, Kg, Vtg, Opart, ml);
    combine<<<128, 256, 0, stream>>>(Opart, ml, out);
}

// Round 5
// 129.076 us; speedup vs baseline: 1.2073x; 1.0774x over previous
//
#include <hip/hip_runtime.h>

typedef __attribute__((ext_vector_type(8))) short bf16x8;
typedef __attribute__((ext_vector_type(4))) float f32x4;

__device__ __forceinline__ unsigned short f2bf(float f) {
    unsigned int u = __float_as_uint(f);
    u += 0x7fffu + ((u >> 16) & 1u);
    return (unsigned short)(u >> 16);
}
__device__ __forceinline__ unsigned int pack2bf(float lo, float hi) {
    return (unsigned int)f2bf(lo) | ((unsigned int)f2bf(hi) << 16);
}
__device__ __forceinline__ void async_ld16(void* lds, const void* g) {
    __builtin_amdgcn_global_load_lds(
        (const __attribute__((address_space(1))) unsigned int*)g,
        (__attribute__((address_space(3))) unsigned int*)lds, 16, 0, 0);
}

// ---------------------------------------------------------------------------
// Kernel 0: convert ONLY the weights Wq/Wk/Wv (f32) -> Wcat (bf16).
// 3*128*1024 = 393216 elems / 8 per thread = 192 blocks x 256.  ~1 us.
// ---------------------------------------------------------------------------
__global__ __launch_bounds__(256) void conv_w(
    const float* __restrict__ Wq, const float* __restrict__ Wk,
    const float* __restrict__ Wv, unsigned short* __restrict__ Wcat)
{
    size_t o = ((size_t)blockIdx.x * 256 + threadIdx.x) * 8;
    int sel = (int)(o >> 17);  // 131072 elems per W
    const float* W = (sel == 0) ? Wq : ((sel == 1) ? Wk : Wv);
    const float* src = W + (o & 131071);
    float4 f0 = ((const float4*)src)[0];
    float4 f1 = ((const float4*)src)[1];
    uint4 u;
    u.x = pack2bf(f0.x, f0.y); u.y = pack2bf(f0.z, f0.w);
    u.z = pack2bf(f1.x, f1.y); u.w = pack2bf(f1.z, f1.w);
    *(uint4*)(Wcat + o) = u;
}

// ---------------------------------------------------------------------------
// Kernel 1: QKV GEMM.  Tile 32(M) x 128(N), BK=64, double-buffered.
// A-tile: staged DIRECTLY from x (f32) with register-prefetched loads +
//   VALU RNE convert + swizzled ds_write_b128 (chunk c of row r at slot
//   c^(r&7) -> same layout as before, frag reads unchanged).
// B-tile: global_load_lds from bf16 Wcat (swizzled source column).
// grid = 768, nb-major (nb = bid>>8) so the 3 sibling blocks sharing an
// x-tile land on the same XCD slot for L2 reuse.
// ---------------------------------------------------------------------------
__global__ __launch_bounds__(256) void qkv_gemm(
    const float* __restrict__ x,
    const unsigned short* __restrict__ Wcat,
    const float* __restrict__ bq, const float* __restrict__ bk,
    const float* __restrict__ bv,
    unsigned short* __restrict__ Qg,
    unsigned short* __restrict__ Kg,
    unsigned short* __restrict__ Vtg)
{
    __shared__ unsigned short As[2][32 * 64];    // 4 KB x2
    __shared__ unsigned short Bs[2][128 * 64];   // 16 KB x2

    const int tid  = threadIdx.x;
    const int lane = tid & 63;
    const int w    = tid >> 6;
    const int quad = lane >> 4;
    const int ln   = lane & 15;
    const int lr   = lane >> 3;                 // 0..7 row-in-chunk (B staging)
    const int csw  = ((lane & 7) ^ lr) * 8;     // B swizzled source col (elems)

    const int bid   = blockIdx.x;
    const int nb    = bid >> 8;                 // 0=Q 1=K 2=V
    const int mbase = (bid & 255) * 32;
    const unsigned short* Wsel = Wcat + (size_t)nb * 128 * 1024;

    // A staging geometry: thread t -> row t>>3 (0..31), chunk t&7 (8 elems)
    const int arow  = tid >> 3;
    const int achk  = tid & 7;
    const int aslot = achk ^ (arow & 7);
    const float* xsrc = x + (size_t)(mbase + arow) * 1024 + achk * 8;
    unsigned short* adst0 = &As[0][arow * 64 + aslot * 8];
    unsigned short* adst1 = &As[1][arow * 64 + aslot * 8];

    f32x4 acc[2][2];
#pragma unroll
    for (int mt = 0; mt < 2; mt++)
#pragma unroll
        for (int nt = 0; nt < 2; nt++) acc[mt][nt] = (f32x4){0.f, 0.f, 0.f, 0.f};

    auto stageB = [&](int kb, int p) {
        const int kcol = kb * 64 + csw;
#pragma unroll
        for (int j = 0; j < 4; j++) {           // 128x64 = 16 chunks of 8 rows
            int chunk = w * 4 + j;
            async_ld16(&Bs[p][chunk * 512 + lane * 8],
                       Wsel + (size_t)(chunk * 8 + lr) * 1024 + kcol);
        }
    };
    auto writeA = [&](int p, const float4& f0, const float4& f1) {
        uint4 u;
        u.x = pack2bf(f0.x, f0.y); u.y = pack2bf(f0.z, f0.w);
        u.z = pack2bf(f1.x, f1.y); u.w = pack2bf(f1.z, f1.w);
        *(uint4*)((p == 0) ? adst0 : adst1) = u;
    };

    // prologue: kb=0
    float4 a0 = ((const float4*)xsrc)[0];
    float4 a1 = ((const float4*)xsrc)[1];
    stageB(0, 0);
    writeA(0, a0, a1);
    __syncthreads();

    for (int kb = 0; kb < 16; kb++) {
        const int p = kb & 1;
        float4 n0, n1;
        if (kb < 15) {
            stageB(kb + 1, p ^ 1);                       // async B prefetch
            const float* xs = xsrc + (kb + 1) * 64;      // reg A prefetch
            n0 = ((const float4*)xs)[0];
            n1 = ((const float4*)xs)[1];
        }
#pragma unroll
        for (int ks = 0; ks < 2; ks++) {
            bf16x8 a[2], b[2];
#pragma unroll
            for (int mt = 0; mt < 2; mt++) {
                int row = mt * 16 + ln;
                a[mt] = *(const bf16x8*)&As[p][row * 64 + ((ks * 4 + quad) ^ (ln & 7)) * 8];
            }
#pragma unroll
            for (int nt = 0; nt < 2; nt++) {
                int row = w * 32 + nt * 16 + ln;
                b[nt] = *(const bf16x8*)&Bs[p][row * 64 + ((ks * 4 + quad) ^ (ln & 7)) * 8];
            }
#pragma unroll
            for (int mt = 0; mt < 2; mt++)
#pragma unroll
                for (int nt = 0; nt < 2; nt++)
                    acc[mt][nt] = __builtin_amdgcn_mfma_f32_16x16x32_bf16(
                        a[mt], b[nt], acc[mt][nt], 0, 0, 0);
        }
        if (kb < 15) writeA(p ^ 1, n0, n1);   // convert+write overlapped prefetch
        __syncthreads();
    }

    const float scale = (nb == 0) ? 0.08838834764831845f : 1.0f;  // 1/sqrt(128)
    const float* bsel = (nb == 0) ? bq : ((nb == 1) ? bk : bv);
    float bias_v[2];
#pragma unroll
    for (int nt = 0; nt < 2; nt++) bias_v[nt] = bsel[w * 32 + nt * 16 + ln];

    if (nb < 2) {
        unsigned short* dst = (nb == 0) ? Qg : Kg;
#pragma unroll
        for (int mt = 0; mt < 2; mt++)
#pragma unroll
            for (int nt = 0; nt < 2; nt++)
#pragma unroll
                for (int r = 0; r < 4; r++) {
                    int m = mbase + mt * 16 + quad * 4 + r;
                    int d = w * 32 + nt * 16 + ln;
                    dst[(size_t)m * 128 + d] =
                        f2bf((acc[mt][nt][r] + bias_v[nt]) * scale);
                }
    } else {
#pragma unroll
        for (int mt = 0; mt < 2; mt++)
#pragma unroll
            for (int nt = 0; nt < 2; nt++) {
                int dd = w * 32 + nt * 16 + ln;
                int m0 = mbase + mt * 16 + quad * 4;
                int bb = m0 >> 11, s0 = m0 & 2047;
                ushort4 u = { f2bf(acc[mt][nt][0] + bias_v[nt]),
                              f2bf(acc[mt][nt][1] + bias_v[nt]),
                              f2bf(acc[mt][nt][2] + bias_v[nt]),
                              f2bf(acc[mt][nt][3] + bias_v[nt]) };
                *(ushort4*)&Vtg[((size_t)bb * 128 + dd) * 2048 + s0] = u;
            }
    }
}

// ---------------------------------------------------------------------------
// Kernel 2: causal flash attention, KV-split, double-buffered swizzled K/V
// staging via global_load_lds; Q in registers.  (unchanged from round 4)
// ---------------------------------------------------------------------------
__global__ __launch_bounds__(256) void flash_attn(
    const unsigned short* __restrict__ Qg,
    const unsigned short* __restrict__ Kg,
    const unsigned short* __restrict__ Vtg,
    unsigned short* __restrict__ Opart,
    float2* __restrict__ ml)
{
    __shared__ unsigned short Ks[2][64 * 128];   // 16 KB x2
    __shared__ unsigned short Vts[2][128 * 64];  // 16 KB x2
    __shared__ unsigned short Pl[64][72];        // 9 KB

    const int b = blockIdx.x;
    const int q = blockIdx.y;
    const int c = blockIdx.z;
    if (c > (q >> 2)) return;

    const int m4 = q >> 2, r4 = q & 3;
    const int pidx = b * 144 + q + 2 * m4 * (m4 - 1) + r4 * m4 + c;
    const int k0 = c * 4;
    const int kend = (c * 4 + 4 < q + 1) ? (c * 4 + 4) : (q + 1);

    const int tid  = threadIdx.x;
    const int lane = tid & 63, w = tid >> 6, quad = lane >> 4, ln = lane & 15;

    // Q A-frags straight into registers (wave w owns q-rows w*16..w*16+15)
    bf16x8 qa[4];
    const unsigned short* qrow =
        Qg + ((size_t)b * 2048 + q * 64 + w * 16 + ln) * 128 + quad * 8;
#pragma unroll
    for (int ks = 0; ks < 4; ks++) qa[ks] = *(const bf16x8*)(qrow + ks * 32);

    auto stage = [&](int kt, int p) {
        // K: 64 rows x 256B = 16 chunks of 1KB (4 rows each), swizzle c^(row&15)
        const unsigned short* ksrc = Kg + ((size_t)b * 2048 + kt * 64) * 128;
        const int krl = lane >> 4;
#pragma unroll
        for (int j = 0; j < 4; j++) {
            int chunk = w * 4 + j;
            int row = chunk * 4 + krl;
            int cd = (lane & 15) ^ (row & 15);
            async_ld16(&Ks[p][chunk * 512 + lane * 8],
                       ksrc + (size_t)row * 128 + cd * 8);
        }
        // Vt: 128 rows x 128B = 8 chunks/row, swizzle c^(row&7)
        const unsigned short* vsrc = Vtg + (size_t)b * 128 * 2048 + kt * 64;
        const int vrl = lane >> 3;
#pragma unroll
        for (int j = 0; j < 4; j++) {
            int chunk = w * 4 + j;
            int row = chunk * 8 + vrl;
            int cd = (lane & 7) ^ (row & 7);
            async_ld16(&Vts[p][chunk * 512 + lane * 8],
                       vsrc + (size_t)row * 2048 + cd * 8);
        }
    };

    float m_i[4], l_i[4];
    f32x4 Ofr[8];
#pragma unroll
    for (int r = 0; r < 4; r++) { m_i[r] = -__builtin_inff(); l_i[r] = 0.f; }
#pragma unroll
    for (int dt = 0; dt < 8; dt++) Ofr[dt] = (f32x4){0.f, 0.f, 0.f, 0.f};

    stage(k0, 0);
    __syncthreads();

    int p = 0;
    for (int kt = k0; kt < kend; kt++) {
        if (kt + 1 < kend) stage(kt + 1, p ^ 1);   // async prefetch

        // S = Q @ K^T  (overlaps the in-flight prefetch)
        f32x4 sfr[4];
#pragma unroll
        for (int ct = 0; ct < 4; ct++) {
            f32x4 s = (f32x4){0.f, 0.f, 0.f, 0.f};
#pragma unroll
            for (int ks = 0; ks < 4; ks++) {
                int row = ct * 16 + ln;
                bf16x8 kf = *(const bf16x8*)&Ks[p][row * 128 + ((ks * 4 + quad) ^ ln) * 8];
                s = __builtin_amdgcn_mfma_f32_16x16x32_bf16(qa[ks], kf, s, 0, 0, 0);
            }
            sfr[ct] = s;
        }

        if (kt == q) {  // diagonal tile: causal mask
#pragma unroll
            for (int ct = 0; ct < 4; ct++)
#pragma unroll
                for (int r = 0; r < 4; r++)
                    if (ct * 16 + ln > w * 16 + quad * 4 + r)
                        sfr[ct][r] = -__builtin_inff();
        }

        // online softmax
        float mrow[4];
#pragma unroll
        for (int r = 0; r < 4; r++) mrow[r] = -__builtin_inff();
#pragma unroll
        for (int ct = 0; ct < 4; ct++)
#pragma unroll
            for (int r = 0; r < 4; r++) mrow[r] = fmaxf(mrow[r], sfr[ct][r]);
#pragma unroll
        for (int off = 1; off < 16; off <<= 1)
#pragma unroll
            for (int r = 0; r < 4; r++)
                mrow[r] = fmaxf(mrow[r], __shfl_xor(mrow[r], off, 64));

        float alpha[4], rs[4];
#pragma unroll
        for (int r = 0; r < 4; r++) {
            float mn = fmaxf(m_i[r], mrow[r]);
            alpha[r] = __expf(m_i[r] - mn);
            m_i[r]   = mn;
            rs[r]    = 0.f;
        }
#pragma unroll
        for (int ct = 0; ct < 4; ct++)
#pragma unroll
            for (int r = 0; r < 4; r++) {
                float pv = __expf(sfr[ct][r] - m_i[r]);
                rs[r] += pv;
                Pl[w * 16 + quad * 4 + r][ct * 16 + ln] = f2bf(pv);
            }
#pragma unroll
        for (int off = 1; off < 16; off <<= 1)
#pragma unroll
            for (int r = 0; r < 4; r++) rs[r] += __shfl_xor(rs[r], off, 64);
#pragma unroll
        for (int r = 0; r < 4; r++) l_i[r] = l_i[r] * alpha[r] + rs[r];
#pragma unroll
        for (int dt = 0; dt < 8; dt++)
#pragma unroll
            for (int r = 0; r < 4; r++) Ofr[dt][r] *= alpha[r];

        __syncthreads();  // Pl visibility; prefetch drain overlapped by S+softmax

        // O += P @ V
#pragma unroll
        for (int kstep = 0; kstep < 2; kstep++) {
            bf16x8 pa = *(const bf16x8*)&Pl[w * 16 + ln][kstep * 32 + quad * 8];
#pragma unroll
            for (int dt = 0; dt < 8; dt++) {
                int row = dt * 16 + ln;
                bf16x8 vf = *(const bf16x8*)&Vts[p][row * 64 + ((kstep * 4 + quad) ^ (ln & 7)) * 8];
                Ofr[dt] = __builtin_amdgcn_mfma_f32_16x16x32_bf16(pa, vf, Ofr[dt], 0, 0, 0);
            }
        }
        __syncthreads();  // WAR on Pl and Vts[p] before next iteration's writes
        p ^= 1;
    }

    // epilogue: unnormalized partials
#pragma unroll
    for (int dt = 0; dt < 8; dt++)
#pragma unroll
        for (int r = 0; r < 4; r++) {
            int row = w * 16 + quad * 4 + r;
            Opart[((size_t)pidx * 64 + row) * 128 + dt * 16 + ln] = f2bf(Ofr[dt][r]);
        }
    if (ln == 0) {
#pragma unroll
        for (int r = 0; r < 4; r++) {
            int row = w * 16 + quad * 4 + r;
            ml[(size_t)pidx * 64 + row] = make_float2(m_i[r], l_i[r]);
        }
    }
}

// ---------------------------------------------------------------------------
// Kernel 3: combine partials.  grid = 256 (b,q,col-half) x 256 threads.
// ---------------------------------------------------------------------------
__global__ __launch_bounds__(256) void combine(
    const unsigned short* __restrict__ Opart,
    const float2* __restrict__ ml,
    float* __restrict__ out)
{
    const int idx  = blockIdx.x >> 1;          // 0..127
    const int half = blockIdx.x & 1;
    const int b = idx >> 5, q = idx & 31;
    const int m4 = q >> 2, r4 = q & 3;
    const int pbase = b * 144 + q + 2 * m4 * (m4 - 1) + r4 * m4;
    const int nc = m4 + 1;

    const int row = threadIdx.x & 63;
    const int grp = half * 64 + (threadIdx.x >> 6) * 16;   // 16 cols per wave

    float2 t[8];
#pragma unroll
    for (int c2 = 0; c2 < 8; c2++) {
        int cc = (c2 < nc) ? c2 : (nc - 1);
        t[c2] = ml[(size_t)(pbase + cc) * 64 + row];
    }
    float mc[8], lc[8], wgt[8];
    float mmax = -__builtin_inff();
#pragma unroll
    for (int c2 = 0; c2 < 8; c2++) {
        mc[c2] = (c2 < nc) ? t[c2].x : -__builtin_inff();
        lc[c2] = (c2 < nc) ? t[c2].y : 0.f;
        mmax = fmaxf(mmax, mc[c2]);
    }
    float lsum = 0.f;
#pragma unroll
    for (int c2 = 0; c2 < 8; c2++) {
        wgt[c2] = __expf(mc[c2] - mmax);   // exp(-inf)=0 for invalid
        lsum += lc[c2] * wgt[c2];
    }
    const float inv = 1.0f / lsum;

#pragma unroll
    for (int v = 0; v < 2; v++) {
        int col = grp + v * 8;
        float acc[8];
#pragma unroll
        for (int k = 0; k < 8; k++) acc[k] = 0.f;
#pragma unroll
        for (int c2 = 0; c2 < 8; c2++) {
            int cc = (c2 < nc) ? c2 : (nc - 1);
            uint4 u = *(const uint4*)&Opart[((size_t)(pbase + cc) * 64 + row) * 128 + col];
            float wc = wgt[c2];
            acc[0] += wc * __uint_as_float(u.x << 16);
            acc[1] += wc * __uint_as_float(u.x & 0xffff0000u);
            acc[2] += wc * __uint_as_float(u.y << 16);
            acc[3] += wc * __uint_as_float(u.y & 0xffff0000u);
            acc[4] += wc * __uint_as_float(u.z << 16);
            acc[5] += wc * __uint_as_float(u.z & 0xffff0000u);
            acc[6] += wc * __uint_as_float(u.w << 16);
            acc[7] += wc * __uint_as_float(u.w & 0xffff0000u);
        }
        float* o = &out[((size_t)b * 2048 + q * 64 + row) * 128 + col];
        float4 o0 = { acc[0] * inv, acc[1] * inv, acc[2] * inv, acc[3] * inv };
        float4 o1 = { acc[4] * inv, acc[5] * inv, acc[6] * inv, acc[7] * inv };
        ((float4*)o)[0] = o0;
        ((float4*)o)[1] = o1;
    }
}

extern "C" void kernel_launch(void* const* d_in, const int* in_sizes, int n_in,
                              void* d_out, int out_size, void* d_ws, size_t ws_size,
                              hipStream_t stream) {
    const float* x  = (const float*)d_in[0];
    const float* Wq = (const float*)d_in[1];
    const float* bq = (const float*)d_in[2];
    const float* Wk = (const float*)d_in[3];
    const float* bk = (const float*)d_in[4];
    const float* Wv = (const float*)d_in[5];
    const float* bv = (const float*)d_in[6];
    float* out = (float*)d_out;

    // Workspace layout (no aliasing needed):
    //   [0, 9437184)            Opart (9 MB)
    //   [9437184, 9732096)      ml (288 KB)
    //   [10485760, 11272192)    Wcat bf16 (768 KB)
    //   [11272192, +6 MB)       Qg / Kg / Vtg (2 MB each)
    char* wsb = (char*)d_ws;
    unsigned short* Opart = (unsigned short*)wsb;
    float2*         ml    = (float2*)(wsb + 9437184);
    unsigned short* Wcat  = (unsigned short*)(wsb + 10485760);
    unsigned short* Qg    = (unsigned short*)(wsb + 11272192);
    unsigned short* Kg    = Qg + (size_t)8192 * 128;
    unsigned short* Vtg   = Qg + (size_t)2 * 8192 * 128;

    conv_w<<<192, 256, 0, stream>>>(Wq, Wk, Wv, Wcat);
    qkv_gemm<<<768, 256, 0, stream>>>(x, Wcat, bq, bk, bv, Qg, Kg, Vtg);
    flash_attn<<<dim3(4, 32, 8), 256, 0, stream>>>(Qg, Kg, Vtg, Opart, ml);
    combine<<<256, 256, 0, stream>>>(Opart, ml, out);
}